// Round 1
// baseline (721.281 us; speedup 1.0000x reference)
//
#include <hip/hip_runtime.h>
#include <stdint.h>

#define Hh   51
#define Bsz  1024
#define Tin  512
#define Ttot 576      // Tin + future(64)
#define NBB  16       // batches per block (grid 64)
#define NW   13       // waves per block; each wave owns ONE M-tile (13 covers 204 rows)
#define BLK  (NW*64)  // 832
#define BST  136      // per-batch k-stride (uint16) = 68 dwords (no 4-way alias)

#define L2E   1.4426950408889634f    // log2(e)
#define TL2E  2.8853900817779268f    // 2*log2(e)

typedef __attribute__((ext_vector_type(8))) short short8;   // 8 x bf16 frag
typedef __attribute__((ext_vector_type(4))) float f32x4;    // C/D frag

__device__ __forceinline__ float rcpf(float x){ return __builtin_amdgcn_rcpf(x); }
__device__ __forceinline__ float exp2f_fast(float x){
#if __has_builtin(__builtin_amdgcn_exp2f)
    return __builtin_amdgcn_exp2f(x);
#else
    return exp2f(x);
#endif
}
__device__ __forceinline__ float sig2(float vp){          // sigmoid(v), vp=v*log2e
    return rcpf(1.f + exp2f_fast(-vp));
}
__device__ __forceinline__ float tanh2(float vp){         // tanh(v), vp=v*2log2e
    return __builtin_fmaf(2.f, rcpf(1.f + exp2f_fast(-vp)), -1.f);
}
__device__ __forceinline__ uint16_t f2bf(float f){
    union{float f;uint32_t u;} v; v.f=f;
    return (uint16_t)((v.u + 0x7fffu + ((v.u>>16)&1u)) >> 16);   // RNE
}
__device__ __forceinline__ float bf2f(uint16_t h){
    union{uint32_t u;float f;} v; v.u=(uint32_t)h<<16; return v.f;
}
#define MFMA __builtin_amdgcn_mfma_f32_16x16x32_bf16

// R15: latency-bound fix. Re-shard 13 M-tiles as 13 waves x 1 tile (was 7 waves
// x 2 tiles): per-wave serial chain per step halves, waves/SIMD 1.75 -> 3.25 for
// latency hiding, wave-6 imbalance gone. L2 GEMM now uses 4 accumulators (MFMA
// dependent chain depth 4 -> 2, tree add at end). Phase fusion, parity double
// buffer, 2-product split-bf16 weights, exp2-folded activations all unchanged.
__global__ __launch_bounds__(BLK)
void lstm_mfma9(const float* __restrict__ inp,    // [B, Tin]
                const float* __restrict__ Wih1,   // [204, 1]
                const float* __restrict__ Whh1,   // [204, 51]
                const float* __restrict__ bih1,   // [204]
                const float* __restrict__ bhh1,   // [204]
                const float* __restrict__ Wih2,   // [204, 51]
                const float* __restrict__ Whh2,   // [204, 51]
                const float* __restrict__ bih2,   // [204]
                const float* __restrict__ bhh2,   // [204]
                const float* __restrict__ Wl,     // [1, 51]
                const float* __restrict__ blp,    // [1]
                float* __restrict__ outp)         // [B, Ttot]
{
    const int tid = threadIdx.x;
    const int wv  = tid >> 6, ln = tid & 63;
    const int quad = ln >> 4, nn = ln & 15;
    const int b0  = blockIdx.x * NBB;

    __shared__ __align__(16) uint16_t Bh[2][NBB*BST];
    __shared__ float wsum[2][NW*17];      // parity-dbuf output partials

    for (int k = tid; k < NBB*BST; k += BLK) { Bh[0][k] = 0; Bh[1][k] = 0; }
    if (tid < NW*17) { wsum[0][tid] = 0.f; wsum[1][tid] = 0.f; }

    // ---- A fragments for this wave's single M-tile; weights pre-scaled by
    // log2e (2log2e for g rows), split bf16 hi/lo (2-product emulation) ----
    short8 a1hi[2], a1lo[2], a2hi[4], a2lo[4];
    f32x4 bias1, bias2, wih1v;

    const int lr = 16*wv + nn;            // A-fragment gate-row for this lane
    const int ua = lr >> 2, ga = lr & 3;
    const bool av = (ua < Hh);
    const int pr = av ? (ga*Hh + ua) : 0;
    const float rs = (ga == 2) ? TL2E : L2E;
#pragma unroll
    for (int s = 0; s < 2; ++s)
#pragma unroll
        for (int j = 0; j < 8; ++j) {
            int k = 32*s + quad*8 + j;
            float w = (av && k < Hh) ? Whh1[pr*Hh + k]*rs : 0.f;
            uint16_t hh = f2bf(w);
            a1hi[s][j] = (short)hh;
            a1lo[s][j] = (short)f2bf(w - bf2f(hh));
        }
#pragma unroll
    for (int s = 0; s < 4; ++s)
#pragma unroll
        for (int j = 0; j < 8; ++j) {
            int k = 32*s + quad*8 + j;
            float w = 0.f;
            if (av) {
                if (k < Hh)                    w = Wih2[pr*Hh + k]*rs;
                else if (k >= 64 && k < 64+Hh) w = Whh2[pr*Hh + (k-64)]*rs;
            }
            uint16_t hh = f2bf(w);
            a2hi[s][j] = (short)hh;
            a2lo[s][j] = (short)f2bf(w - bf2f(hh));
        }
    const int u = 4*wv + quad;            // hidden unit owned by this lane
    const bool uv = (u < Hh);
#pragma unroll
    for (int i = 0; i < 4; ++i) {
        int pri = uv ? (i*Hh + u) : 0;
        float gs = (i == 2) ? TL2E : L2E;
        bias1[i] = uv ? (bih1[pri] + bhh1[pri])*gs : 0.f;
        bias2[i] = uv ? (bih2[pri] + bhh2[pri])*gs : 0.f;
        wih1v[i] = uv ? Wih1[pri]*gs : 0.f;
    }
    const float wlu = uv ? Wl[u] : 0.f;
    const float blv = blp[0];
    float c1 = 0.f, c2 = 0.f;

    // ---- prologue: h1(0) = cell(c1=0, b1 + x0*wih1) -> Bh[0] ----
    {
        float x0 = inp[(size_t)(b0 + nn)*Tin];
        float vi = __builtin_fmaf(wih1v[0], x0, bias1[0]);
        float vg = __builtin_fmaf(wih1v[2], x0, bias1[2]);
        float vo = __builtin_fmaf(wih1v[3], x0, bias1[3]);
        c1 = sig2(vi) * tanh2(vg);
        float h1n = sig2(vo) * tanh2(c1*TL2E);
        if (uv) Bh[0][nn*BST + u] = f2bf(h1n);
    }
    float xreg = (Tin > 1) ? inp[(size_t)(b0 + nn)*Tin + 1] : 0.f;  // x(1)
    __syncthreads();

    for (int t = 0; t < Ttot; ++t) {
        const int cur = t & 1, nxt = cur ^ 1;
        const bool inmode = (t + 1 < Tin);

        // out(t-1) write (wave NW-1, reads previous phase's wsum[nxt])
        if (wv == NW-1 && t > 0) {
            float osum = blv;
#pragma unroll
            for (int w = 0; w < NW; ++w) osum += wsum[nxt][w*17 + nn];
            if (ln < NBB) outp[(size_t)(b0 + ln)*Ttot + (t-1)] = osum;
        }
        float xn = (t + 2 < Tin) ? inp[(size_t)(b0 + nn)*Tin + t + 2] : 0.f;

        // ---- one LDS read session: h1(t) slabs 0,1 + h2(t-1) slabs 2,3 ----
        const uint16_t* rb = &Bh[cur][nn*BST + quad*8];
        short8 s0 = *(const short8*)(rb),      s1 = *(const short8*)(rb + 32);
        short8 s2 = *(const short8*)(rb + 64), s3 = *(const short8*)(rb + 96);

        // ================= L2(t): GEMM (4 accums, depth-2) + cell =========
        {
            f32x4 aA = bias2;
            f32x4 aB = {0.f,0.f,0.f,0.f}, aC = {0.f,0.f,0.f,0.f}, aD = {0.f,0.f,0.f,0.f};
            aA = MFMA(a2hi[0], s0, aA, 0,0,0);
            aB = MFMA(a2hi[1], s1, aB, 0,0,0);
            aC = MFMA(a2hi[2], s2, aC, 0,0,0);
            aD = MFMA(a2hi[3], s3, aD, 0,0,0);
            aA = MFMA(a2lo[0], s0, aA, 0,0,0);
            aB = MFMA(a2lo[1], s1, aB, 0,0,0);
            aC = MFMA(a2lo[2], s2, aC, 0,0,0);
            aD = MFMA(a2lo[3], s3, aD, 0,0,0);
            f32x4 g = (aA + aB) + (aC + aD);
            float vi = g[0], vf = g[1], vg = g[2], vo = g[3];
            c2 = __builtin_fmaf(sig2(vf), c2, sig2(vi)*tanh2(vg));
            float h2v = sig2(vo) * tanh2(c2*TL2E);
            if (uv) Bh[nxt][nn*BST + 64 + u] = f2bf(h2v);
            float part = wlu * h2v;
            part += __shfl_xor(part, 16, 64);
            part += __shfl_xor(part, 32, 64);
            if (quad == 0) wsum[cur][wv*17 + nn] = part;
        }

        // ========= L1(t+1) fused (input mode: x already in register) =========
        if (inmode) {
            f32x4 aA, aB = {0.f,0.f,0.f,0.f};
#pragma unroll
            for (int i = 0; i < 4; ++i)
                aA[i] = __builtin_fmaf(wih1v[i], xreg, bias1[i]);
            aA = MFMA(a1hi[0], s0, aA, 0,0,0);
            aB = MFMA(a1hi[1], s1, aB, 0,0,0);
            aA = MFMA(a1lo[0], s0, aA, 0,0,0);
            aB = MFMA(a1lo[1], s1, aB, 0,0,0);
            float vi = aA[0]+aB[0], vf = aA[1]+aB[1];
            float vg = aA[2]+aB[2], vo = aA[3]+aB[3];
            c1 = __builtin_fmaf(sig2(vf), c1, sig2(vi)*tanh2(vg));
            float h1n = sig2(vo) * tanh2(c1*TL2E);
            if (uv) Bh[nxt][nn*BST + u] = f2bf(h1n);
        }
        __syncthreads();                                   // bar 1

        // ===== future sub-phase: x(t+1) = out(t), then L1(t+1) =====
        if (!inmode && t + 1 < Ttot) {
            float osum = blv;
#pragma unroll
            for (int w = 0; w < NW; ++w) osum += wsum[cur][w*17 + nn];
            f32x4 aA, aB = {0.f,0.f,0.f,0.f};
#pragma unroll
            for (int i = 0; i < 4; ++i)
                aA[i] = __builtin_fmaf(wih1v[i], osum, bias1[i]);
            aA = MFMA(a1hi[0], s0, aA, 0,0,0);   // s0,s1 still live
            aB = MFMA(a1hi[1], s1, aB, 0,0,0);
            aA = MFMA(a1lo[0], s0, aA, 0,0,0);
            aB = MFMA(a1lo[1], s1, aB, 0,0,0);
            float vi = aA[0]+aB[0], vf = aA[1]+aB[1];
            float vg = aA[2]+aB[2], vo = aA[3]+aB[3];
            c1 = __builtin_fmaf(sig2(vf), c1, sig2(vi)*tanh2(vg));
            float h1n = sig2(vo) * tanh2(c1*TL2E);
            if (uv) Bh[nxt][nn*BST + u] = f2bf(h1n);
            __syncthreads();                               // bar 2 (future only)
        }
        xreg = xn;
    }

    // final output (t = Ttot-1): wsum[(Ttot-1)&1] visible after last barrier
    if (wv == NW-1) {
        float osum = blv;
#pragma unroll
        for (int w = 0; w < NW; ++w) osum += wsum[(Ttot-1)&1][w*17 + nn];
        if (ln < NBB) outp[(size_t)(b0 + ln)*Ttot + (Ttot-1)] = osum;
    }
}

extern "C" void kernel_launch(void* const* d_in, const int* in_sizes, int n_in,
                              void* d_out, int out_size, void* d_ws, size_t ws_size,
                              hipStream_t stream) {
    (void)in_sizes; (void)n_in; (void)out_size; (void)d_ws; (void)ws_size;
    lstm_mfma9<<<dim3(Bsz / NBB), dim3(BLK), 0, stream>>>(
        (const float*)d_in[0], (const float*)d_in[1],
        (const float*)d_in[2], (const float*)d_in[3],
        (const float*)d_in[4], (const float*)d_in[5],
        (const float*)d_in[6], (const float*)d_in[7],
        (const float*)d_in[8], (const float*)d_in[9],
        (const float*)d_in[10], (float*)d_out);
}

// Round 2
// 645.130 us; speedup vs baseline: 1.1180x; 1.1180x over previous
//
#include <hip/hip_runtime.h>
#include <stdint.h>

#define Hh   51
#define Bsz  1024
#define Tin  512
#define Ttot 576      // Tin + future(64)
#define NBB  16       // batches per block (grid 64)
#define NW   7        // waves per block; each wave owns 2 M-tiles (14 >= 13)
#define BLK  (NW*64)  // 448
#define BST  136      // per-batch k-stride (uint16) = 68 dwords (no 4-way alias)

#define L2E   1.4426950408889634f    // log2(e)
#define TL2E  2.8853900817779268f    // 2*log2(e)

typedef __attribute__((ext_vector_type(8))) _Float16 half8;  // 8 x f16 frag
typedef __attribute__((ext_vector_type(4))) float f32x4;     // C/D frag

__device__ __forceinline__ float rcpf(float x){ return __builtin_amdgcn_rcpf(x); }
__device__ __forceinline__ float exp2f_fast(float x){
#if __has_builtin(__builtin_amdgcn_exp2f)
    return __builtin_amdgcn_exp2f(x);
#else
    return exp2f(x);
#endif
}

// Fused LSTM pointwise, rcp-merged: 7 trans ops (was 10).
// Inputs pre-scaled: vi,vf,vo by log2e; vg by 2log2e. Updates c, returns h.
//  sig(f)*c + sig(i)*tanh(g) = c*(B*C)*R + (A*D)*R,  R = rcp(A*B*C)
//  A=1+2^-vf, B=1+2^-vi, C=1+2^-vg, D=1-2^-vg
//  h = sig(o)*tanh(c') = (1-Ec)*rcp((1+Eo)*(1+Ec)),  Ec=2^-(2c'*log2e)
// Ec arg clamped to 120 to avoid inf*0 NaN at deep negative c (old code
// saturated gracefully; this keeps that property).
__device__ __forceinline__ float cell_fuse(float vi, float vf, float vg,
                                           float vo, float& c){
    float Ei = exp2f_fast(-vi), Ef = exp2f_fast(-vf), Eg = exp2f_fast(-vg);
    float A = 1.f + Ef, B = 1.f + Ei, C = 1.f + Eg, D = 1.f - Eg;
    float BC = B*C;
    float R  = rcpf(A*BC);
    float cn = __builtin_fmaf(c, BC*R, (A*D)*R);
    c = cn;
    float Ec = exp2f_fast(fminf(-cn*TL2E, 120.f));
    float Eo = exp2f_fast(-vo);
    float R2 = rcpf((1.f+Eo)*(1.f+Ec));
    return (1.f - Ec) * R2;
}

__device__ __forceinline__ uint16_t f2h(float f){
    union{ _Float16 h; uint16_t u; } v; v.h = (_Float16)f;   // v_cvt_f16_f32 RNE
    return v.u;
}
#define MFMA __builtin_amdgcn_mfma_f32_16x16x32_f16

// R16: f16 end-to-end single-product (drop the split-bf16 hi/lo emulation:
// f16 weights AND f16 h both have 2^-11 ulp, 4x better than the bf16 h-storage
// that dominated the old error budget -> absmax should improve while MFMA
// count halves: 12 -> 6 per tile per step). Activation pointwise rcp-merged
// (10 -> 7 trans ops/cell). Structure = known-best NW=7 phase-fused parity-
// double-buffered shape (B-fragment LDS reads amortized over 2 tiles/wave).
__global__ __launch_bounds__(BLK, 2)
void lstm_f16s(const float* __restrict__ inp,    // [B, Tin]
               const float* __restrict__ Wih1,   // [204, 1]
               const float* __restrict__ Whh1,   // [204, 51]
               const float* __restrict__ bih1,   // [204]
               const float* __restrict__ bhh1,   // [204]
               const float* __restrict__ Wih2,   // [204, 51]
               const float* __restrict__ Whh2,   // [204, 51]
               const float* __restrict__ bih2,   // [204]
               const float* __restrict__ bhh2,   // [204]
               const float* __restrict__ Wl,     // [1, 51]
               const float* __restrict__ blp,    // [1]
               float* __restrict__ outp)         // [B, Ttot]
{
    const int tid = threadIdx.x;
    const int wv  = tid >> 6, ln = tid & 63;
    const int quad = ln >> 4, nn = ln & 15;
    const int b0  = blockIdx.x * NBB;

    __shared__ __align__(16) uint16_t Bh[2][NBB*BST];
    __shared__ float wsum[2][NW*17];      // parity-dbuf output partials

    for (int k = tid; k < NBB*BST; k += BLK) { Bh[0][k] = 0; Bh[1][k] = 0; }
    if (tid < NW*17) { wsum[0][tid] = 0.f; wsum[1][tid] = 0.f; }

    // ---- A fragments for 2 tiles; weights pre-scaled by log2e (2log2e for
    // g rows), single f16 product ----
    half8 a1[2][2], a2[2][4];
    f32x4 bias1[2], bias2[2], wih1v[2];
    float wlu[2]; int ut[2]; bool uvt[2], tvt[2];
#pragma unroll
    for (int tl = 0; tl < 2; ++tl) {
        tvt[tl] = (wv + 7*tl) < 13;
        const int lr = 16*(wv + 7*tl) + nn;
        const int ua = lr >> 2, ga = lr & 3;
        const bool av = tvt[tl] && (ua < Hh);
        const int pr = av ? (ga*Hh + ua) : 0;
        const float rs = (ga == 2) ? TL2E : L2E;
#pragma unroll
        for (int s = 0; s < 2; ++s)
#pragma unroll
            for (int j = 0; j < 8; ++j) {
                int k = 32*s + quad*8 + j;
                float w = (av && k < Hh) ? Whh1[pr*Hh + k]*rs : 0.f;
                a1[tl][s][j] = (_Float16)w;
            }
#pragma unroll
        for (int s = 0; s < 4; ++s)
#pragma unroll
            for (int j = 0; j < 8; ++j) {
                int k = 32*s + quad*8 + j;
                float w = 0.f;
                if (av) {
                    if (k < Hh)                    w = Wih2[pr*Hh + k]*rs;
                    else if (k >= 64 && k < 64+Hh) w = Whh2[pr*Hh + (k-64)]*rs;
                }
                a2[tl][s][j] = (_Float16)w;
            }
        const int u = 4*(wv + 7*tl) + quad;
        ut[tl] = u; uvt[tl] = tvt[tl] && (u < Hh);
#pragma unroll
        for (int i = 0; i < 4; ++i) {
            int pri = uvt[tl] ? (i*Hh + u) : 0;
            float gs = (i == 2) ? TL2E : L2E;
            bias1[tl][i] = uvt[tl] ? (bih1[pri] + bhh1[pri])*gs : 0.f;
            bias2[tl][i] = uvt[tl] ? (bih2[pri] + bhh2[pri])*gs : 0.f;
            wih1v[tl][i] = uvt[tl] ? Wih1[pri]*gs : 0.f;
        }
        wlu[tl] = uvt[tl] ? Wl[ut[tl]] : 0.f;
    }
    const float blv = blp[0];
    float c1[2] = {0.f, 0.f}, c2[2] = {0.f, 0.f};

    // ---- prologue: h1(0) = cell(c1=0, b1 + x0*wih1) -> Bh[0] ----
    {
        float x0 = inp[(size_t)(b0 + nn)*Tin];
#pragma unroll
        for (int tl = 0; tl < 2; ++tl) {
            float vi = __builtin_fmaf(wih1v[tl][0], x0, bias1[tl][0]);
            float vf = __builtin_fmaf(wih1v[tl][1], x0, bias1[tl][1]);
            float vg = __builtin_fmaf(wih1v[tl][2], x0, bias1[tl][2]);
            float vo = __builtin_fmaf(wih1v[tl][3], x0, bias1[tl][3]);
            float h1n = cell_fuse(vi, vf, vg, vo, c1[tl]);   // c1=0: f-term nil
            if (uvt[tl]) Bh[0][nn*BST + ut[tl]] = f2h(h1n);
        }
    }
    float xreg = (Tin > 1) ? inp[(size_t)(b0 + nn)*Tin + 1] : 0.f;  // x(1)
    __syncthreads();

    for (int t = 0; t < Ttot; ++t) {
        const int cur = t & 1, nxt = cur ^ 1;
        const bool inmode = (t + 1 < Tin);

        // out(t-1) write (wave NW-1, reads previous phase's wsum[nxt])
        if (wv == NW-1 && t > 0) {
            float osum = blv;
#pragma unroll
            for (int w = 0; w < NW; ++w) osum += wsum[nxt][w*17 + nn];
            if (ln < NBB) outp[(size_t)(b0 + ln)*Ttot + (t-1)] = osum;
        }
        float xn = (t + 2 < Tin) ? inp[(size_t)(b0 + nn)*Tin + t + 2] : 0.f;

        // ---- one LDS read session: h1(t) slabs 0,1 + h2(t-1) slabs 2,3 ----
        const uint16_t* rb = &Bh[cur][nn*BST + quad*8];
        half8 s0 = *(const half8*)(rb),      s1 = *(const half8*)(rb + 32);
        half8 s2 = *(const half8*)(rb + 64), s3 = *(const half8*)(rb + 96);

        // ================= L2(t): GEMM + cells + wsum =================
        {
            float h2v[2] = {0.f, 0.f};
#pragma unroll
            for (int tl = 0; tl < 2; ++tl) {
                if (!tvt[tl]) continue;
                f32x4 aA = bias2[tl], aB = {0.f,0.f,0.f,0.f};
                aA = MFMA(a2[tl][0], s0, aA, 0,0,0);
                aB = MFMA(a2[tl][1], s1, aB, 0,0,0);
                aA = MFMA(a2[tl][2], s2, aA, 0,0,0);
                aB = MFMA(a2[tl][3], s3, aB, 0,0,0);
                float vi = aA[0]+aB[0], vf = aA[1]+aB[1];
                float vg = aA[2]+aB[2], vo = aA[3]+aB[3];
                h2v[tl] = cell_fuse(vi, vf, vg, vo, c2[tl]);
                if (uvt[tl]) Bh[nxt][nn*BST + 64 + ut[tl]] = f2h(h2v[tl]);
            }
            float part = __builtin_fmaf(wlu[0], h2v[0], wlu[1]*h2v[1]);
            part += __shfl_xor(part, 16, 64);
            part += __shfl_xor(part, 32, 64);
            if (quad == 0) wsum[cur][wv*17 + nn] = part;
        }

        // ========= L1(t+1) fused (input mode: x already in register) =========
        if (inmode) {
#pragma unroll
            for (int tl = 0; tl < 2; ++tl) {
                if (!tvt[tl]) continue;
                f32x4 aA, aB = {0.f,0.f,0.f,0.f};
#pragma unroll
                for (int i = 0; i < 4; ++i)
                    aA[i] = __builtin_fmaf(wih1v[tl][i], xreg, bias1[tl][i]);
                aA = MFMA(a1[tl][0], s0, aA, 0,0,0);
                aB = MFMA(a1[tl][1], s1, aB, 0,0,0);
                float vi = aA[0]+aB[0], vf = aA[1]+aB[1];
                float vg = aA[2]+aB[2], vo = aA[3]+aB[3];
                float h1n = cell_fuse(vi, vf, vg, vo, c1[tl]);
                if (uvt[tl]) Bh[nxt][nn*BST + ut[tl]] = f2h(h1n);
            }
        }
        __syncthreads();                                   // bar 1

        // ===== future sub-phase: x(t+1) = out(t), then L1(t+1) =====
        if (!inmode && t + 1 < Ttot) {
            float osum = blv;
#pragma unroll
            for (int w = 0; w < NW; ++w) osum += wsum[cur][w*17 + nn];
#pragma unroll
            for (int tl = 0; tl < 2; ++tl) {
                if (!tvt[tl]) continue;
                f32x4 aA, aB = {0.f,0.f,0.f,0.f};
#pragma unroll
                for (int i = 0; i < 4; ++i)
                    aA[i] = __builtin_fmaf(wih1v[tl][i], osum, bias1[tl][i]);
                aA = MFMA(a1[tl][0], s0, aA, 0,0,0);   // s0,s1 still live
                aB = MFMA(a1[tl][1], s1, aB, 0,0,0);
                float vi = aA[0]+aB[0], vf = aA[1]+aB[1];
                float vg = aA[2]+aB[2], vo = aA[3]+aB[3];
                float h1n = cell_fuse(vi, vf, vg, vo, c1[tl]);
                if (uvt[tl]) Bh[nxt][nn*BST + ut[tl]] = f2h(h1n);
            }
            __syncthreads();                               // bar 2 (future only)
        }
        xreg = xn;
    }

    // final output (t = Ttot-1): wsum[(Ttot-1)&1] visible after last barrier
    if (wv == NW-1) {
        float osum = blv;
#pragma unroll
        for (int w = 0; w < NW; ++w) osum += wsum[(Ttot-1)&1][w*17 + nn];
        if (ln < NBB) outp[(size_t)(b0 + ln)*Ttot + (Ttot-1)] = osum;
    }
}

extern "C" void kernel_launch(void* const* d_in, const int* in_sizes, int n_in,
                              void* d_out, int out_size, void* d_ws, size_t ws_size,
                              hipStream_t stream) {
    (void)in_sizes; (void)n_in; (void)out_size; (void)d_ws; (void)ws_size;
    lstm_f16s<<<dim3(Bsz / NBB), dim3(BLK), 0, stream>>>(
        (const float*)d_in[0], (const float*)d_in[1],
        (const float*)d_in[2], (const float*)d_in[3],
        (const float*)d_in[4], (const float*)d_in[5],
        (const float*)d_in[6], (const float*)d_in[7],
        (const float*)d_in[8], (const float*)d_in[9],
        (const float*)d_in[10], (float*)d_out);
}

// Round 3
// 581.828 us; speedup vs baseline: 1.2397x; 1.1088x over previous
//
#include <hip/hip_runtime.h>
#include <stdint.h>

#define Hh   51
#define Bsz  1024
#define Tin  512
#define Ttot 576      // Tin + future(64)
#define NBB  16       // batches per block (grid 64)
#define NW   7        // waves per block; each wave owns 2 M-tiles (14 >= 13)
#define BLK  (NW*64)  // 448
#define BST  136      // per-batch k-stride (uint16) = 68 dwords (no 4-way alias)

#define L2E   1.4426950408889634f    // log2(e)
#define TL2E  2.8853900817779268f    // 2*log2(e)

typedef __attribute__((ext_vector_type(8))) _Float16 half8;  // 8 x f16 frag
typedef __attribute__((ext_vector_type(4))) float f32x4;     // C/D frag

__device__ __forceinline__ float rcpf(float x){ return __builtin_amdgcn_rcpf(x); }
__device__ __forceinline__ float exp2f_fast(float x){
#if __has_builtin(__builtin_amdgcn_exp2f)
    return __builtin_amdgcn_exp2f(x);
#else
    return exp2f(x);
#endif
}

// Fused LSTM pointwise, rcp-merged: 7 trans ops.
// Inputs pre-scaled: vi,vf,vo by log2e; vg by 2log2e. Updates c, returns h.
__device__ __forceinline__ float cell_fuse(float vi, float vf, float vg,
                                           float vo, float& c){
    float Ei = exp2f_fast(-vi), Ef = exp2f_fast(-vf), Eg = exp2f_fast(-vg);
    float A = 1.f + Ef, B = 1.f + Ei, C = 1.f + Eg, D = 1.f - Eg;
    float BC = B*C;
    float R  = rcpf(A*BC);
    float cn = __builtin_fmaf(c, BC*R, (A*D)*R);
    c = cn;
    float Ec = exp2f_fast(fminf(-cn*TL2E, 120.f));
    float Eo = exp2f_fast(-vo);
    float R2 = rcpf((1.f+Eo)*(1.f+Ec));
    return (1.f - Ec) * R2;
}

__device__ __forceinline__ uint16_t f2h(float f){
    union{ _Float16 h; uint16_t u; } v; v.h = (_Float16)f;   // v_cvt_f16_f32 RNE
    return v.u;
}
#define MFMA __builtin_amdgcn_mfma_f32_16x16x32_f16

// R17: single-scheduling-region step body. Loop split input/future (inmode
// branch gone from 511 hot iters), tvt wave-uniform skips removed (wave 6
// computes harmless zero tile; stores stay lane-predicated), all 12 MFMAs
// issued flat (6 independent depth-2 chains), then 4 independent cell_fuse
// chains together so the trans/rcp latency is hidden by ILP (only 1.75
// waves/SIMD exist -> TLP can't hide it). Numerics identical to R16.
__global__ __launch_bounds__(BLK, 2)
void lstm_f16t(const float* __restrict__ inp,    // [B, Tin]
               const float* __restrict__ Wih1,   // [204, 1]
               const float* __restrict__ Whh1,   // [204, 51]
               const float* __restrict__ bih1,   // [204]
               const float* __restrict__ bhh1,   // [204]
               const float* __restrict__ Wih2,   // [204, 51]
               const float* __restrict__ Whh2,   // [204, 51]
               const float* __restrict__ bih2,   // [204]
               const float* __restrict__ bhh2,   // [204]
               const float* __restrict__ Wl,     // [1, 51]
               const float* __restrict__ blp,    // [1]
               float* __restrict__ outp)         // [B, Ttot]
{
    const int tid = threadIdx.x;
    const int wv  = tid >> 6, ln = tid & 63;
    const int quad = ln >> 4, nn = ln & 15;
    const int b0  = blockIdx.x * NBB;

    __shared__ __align__(16) uint16_t Bh[2][NBB*BST];
    __shared__ float wsum[2][NW*17];      // parity-dbuf output partials

    for (int k = tid; k < NBB*BST; k += BLK) { Bh[0][k] = 0; Bh[1][k] = 0; }
    if (tid < NW*17) { wsum[0][tid] = 0.f; wsum[1][tid] = 0.f; }

    // ---- A fragments for 2 tiles; weights pre-scaled by log2e (2log2e for
    // g rows), single f16 product. Wave 6 tile 1 = all-zero dummy. ----
    half8 a1[2][2], a2[2][4];
    f32x4 bias1[2], bias2[2], wih1v[2];
    float wlu[2]; int ut[2]; bool uvt[2];
#pragma unroll
    for (int tl = 0; tl < 2; ++tl) {
        const bool tv = (wv + 7*tl) < 13;
        const int lr = 16*(wv + 7*tl) + nn;
        const int ua = lr >> 2, ga = lr & 3;
        const bool av = tv && (ua < Hh);
        const int pr = av ? (ga*Hh + ua) : 0;
        const float rs = (ga == 2) ? TL2E : L2E;
#pragma unroll
        for (int s = 0; s < 2; ++s)
#pragma unroll
            for (int j = 0; j < 8; ++j) {
                int k = 32*s + quad*8 + j;
                float w = (av && k < Hh) ? Whh1[pr*Hh + k]*rs : 0.f;
                a1[tl][s][j] = (_Float16)w;
            }
#pragma unroll
        for (int s = 0; s < 4; ++s)
#pragma unroll
            for (int j = 0; j < 8; ++j) {
                int k = 32*s + quad*8 + j;
                float w = 0.f;
                if (av) {
                    if (k < Hh)                    w = Wih2[pr*Hh + k]*rs;
                    else if (k >= 64 && k < 64+Hh) w = Whh2[pr*Hh + (k-64)]*rs;
                }
                a2[tl][s][j] = (_Float16)w;
            }
        const int u = 4*(wv + 7*tl) + quad;
        ut[tl] = u; uvt[tl] = tv && (u < Hh);
#pragma unroll
        for (int i = 0; i < 4; ++i) {
            int pri = uvt[tl] ? (i*Hh + u) : 0;
            float gs = (i == 2) ? TL2E : L2E;
            bias1[tl][i] = uvt[tl] ? (bih1[pri] + bhh1[pri])*gs : 0.f;
            bias2[tl][i] = uvt[tl] ? (bih2[pri] + bhh2[pri])*gs : 0.f;
            wih1v[tl][i] = uvt[tl] ? Wih1[pri]*gs : 0.f;
        }
        wlu[tl] = uvt[tl] ? Wl[ut[tl]] : 0.f;
    }
    const float blv = blp[0];
    float c1[2] = {0.f, 0.f}, c2[2] = {0.f, 0.f};

    // ---- prologue: h1(0) = cell(c1=0, b1 + x0*wih1) -> Bh[0] ----
    {
        float x0 = inp[(size_t)(b0 + nn)*Tin];
#pragma unroll
        for (int tl = 0; tl < 2; ++tl) {
            float vi = __builtin_fmaf(wih1v[tl][0], x0, bias1[tl][0]);
            float vf = __builtin_fmaf(wih1v[tl][1], x0, bias1[tl][1]);
            float vg = __builtin_fmaf(wih1v[tl][2], x0, bias1[tl][2]);
            float vo = __builtin_fmaf(wih1v[tl][3], x0, bias1[tl][3]);
            float h1n = cell_fuse(vi, vf, vg, vo, c1[tl]);   // c1=0: f-term nil
            if (uvt[tl]) Bh[0][nn*BST + ut[tl]] = f2h(h1n);
        }
    }
    float xreg = (Tin > 1) ? inp[(size_t)(b0 + nn)*Tin + 1] : 0.f;  // x(1)
    __syncthreads();

    // ================= input-mode loop: t in [0, Tin-1) =================
    for (int t = 0; t < Tin-1; ++t) {
        const int cur = t & 1, nxt = cur ^ 1;

        // out(t-1) write (wave NW-1 only; reads previous phase's wsum[nxt])
        if (wv == NW-1 && t > 0) {
            float osum = blv;
#pragma unroll
            for (int w = 0; w < NW; ++w) osum += wsum[nxt][w*17 + nn];
            if (ln < NBB) outp[(size_t)(b0 + ln)*Ttot + (t-1)] = osum;
        }
        // branchless x(t+2) prefetch (clamped load + select)
        const int tc = (t + 2 < Tin) ? t + 2 : Tin - 1;
        float xl = inp[(size_t)(b0 + nn)*Tin + tc];
        float xn = (t + 2 < Tin) ? xl : 0.f;

        // ---- one LDS read session: h1(t) slabs 0,1 + h2(t-1) slabs 2,3 ----
        const uint16_t* rb = &Bh[cur][nn*BST + quad*8];
        half8 s0 = *(const half8*)(rb),      s1 = *(const half8*)(rb + 32);
        half8 s2 = *(const half8*)(rb + 64), s3 = *(const half8*)(rb + 96);

        // ---- flat MFMA issue: L2(t) both tiles + L1(t+1) both tiles ----
        f32x4 aA0 = bias2[0], aB0 = {0.f,0.f,0.f,0.f};
        f32x4 aA1 = bias2[1], aB1 = {0.f,0.f,0.f,0.f};
        f32x4 bA0, bA1, bB0 = {0.f,0.f,0.f,0.f}, bB1 = {0.f,0.f,0.f,0.f};
#pragma unroll
        for (int i = 0; i < 4; ++i) {
            bA0[i] = __builtin_fmaf(wih1v[0][i], xreg, bias1[0][i]);
            bA1[i] = __builtin_fmaf(wih1v[1][i], xreg, bias1[1][i]);
        }
        aA0 = MFMA(a2[0][0], s0, aA0, 0,0,0);  aB0 = MFMA(a2[0][1], s1, aB0, 0,0,0);
        aA1 = MFMA(a2[1][0], s0, aA1, 0,0,0);  aB1 = MFMA(a2[1][1], s1, aB1, 0,0,0);
        bA0 = MFMA(a1[0][0], s0, bA0, 0,0,0);  bB0 = MFMA(a1[0][1], s1, bB0, 0,0,0);
        bA1 = MFMA(a1[1][0], s0, bA1, 0,0,0);  bB1 = MFMA(a1[1][1], s1, bB1, 0,0,0);
        aA0 = MFMA(a2[0][2], s2, aA0, 0,0,0);  aB0 = MFMA(a2[0][3], s3, aB0, 0,0,0);
        aA1 = MFMA(a2[1][2], s2, aA1, 0,0,0);  aB1 = MFMA(a2[1][3], s3, aB1, 0,0,0);

        // ---- 4 independent cell chains (ILP hides trans latency) ----
        f32x4 g20 = aA0 + aB0, g21 = aA1 + aB1;
        f32x4 g10 = bA0 + bB0, g11 = bA1 + bB1;
        float h2v0 = cell_fuse(g20[0], g20[1], g20[2], g20[3], c2[0]);
        float h2v1 = cell_fuse(g21[0], g21[1], g21[2], g21[3], c2[1]);
        float h1n0 = cell_fuse(g10[0], g10[1], g10[2], g10[3], c1[0]);
        float h1n1 = cell_fuse(g11[0], g11[1], g11[2], g11[3], c1[1]);

        if (uvt[0]) {
            Bh[nxt][nn*BST + 64 + ut[0]] = f2h(h2v0);
            Bh[nxt][nn*BST      + ut[0]] = f2h(h1n0);
        }
        if (uvt[1]) {
            Bh[nxt][nn*BST + 64 + ut[1]] = f2h(h2v1);
            Bh[nxt][nn*BST      + ut[1]] = f2h(h1n1);
        }
        float part = __builtin_fmaf(wlu[0], h2v0, wlu[1]*h2v1);
        part += __shfl_xor(part, 16, 64);
        part += __shfl_xor(part, 32, 64);
        if (quad == 0) wsum[cur][wv*17 + nn] = part;

        __syncthreads();
        xreg = xn;
    }

    // ================= future loop: t in [Tin-1, Ttot) =================
    for (int t = Tin-1; t < Ttot; ++t) {
        const int cur = t & 1, nxt = cur ^ 1;

        if (wv == NW-1) {       // t >= 511 > 0 always
            float osum = blv;
#pragma unroll
            for (int w = 0; w < NW; ++w) osum += wsum[nxt][w*17 + nn];
            if (ln < NBB) outp[(size_t)(b0 + ln)*Ttot + (t-1)] = osum;
        }

        const uint16_t* rb = &Bh[cur][nn*BST + quad*8];
        half8 s0 = *(const half8*)(rb),      s1 = *(const half8*)(rb + 32);
        half8 s2 = *(const half8*)(rb + 64), s3 = *(const half8*)(rb + 96);

        // ---- L2(t), both tiles flat ----
        f32x4 aA0 = bias2[0], aB0 = {0.f,0.f,0.f,0.f};
        f32x4 aA1 = bias2[1], aB1 = {0.f,0.f,0.f,0.f};
        aA0 = MFMA(a2[0][0], s0, aA0, 0,0,0);  aB0 = MFMA(a2[0][1], s1, aB0, 0,0,0);
        aA1 = MFMA(a2[1][0], s0, aA1, 0,0,0);  aB1 = MFMA(a2[1][1], s1, aB1, 0,0,0);
        aA0 = MFMA(a2[0][2], s2, aA0, 0,0,0);  aB0 = MFMA(a2[0][3], s3, aB0, 0,0,0);
        aA1 = MFMA(a2[1][2], s2, aA1, 0,0,0);  aB1 = MFMA(a2[1][3], s3, aB1, 0,0,0);
        f32x4 g20 = aA0 + aB0, g21 = aA1 + aB1;
        float h2v0 = cell_fuse(g20[0], g20[1], g20[2], g20[3], c2[0]);
        float h2v1 = cell_fuse(g21[0], g21[1], g21[2], g21[3], c2[1]);
        if (uvt[0]) Bh[nxt][nn*BST + 64 + ut[0]] = f2h(h2v0);
        if (uvt[1]) Bh[nxt][nn*BST + 64 + ut[1]] = f2h(h2v1);
        float part = __builtin_fmaf(wlu[0], h2v0, wlu[1]*h2v1);
        part += __shfl_xor(part, 16, 64);
        part += __shfl_xor(part, 32, 64);
        if (quad == 0) wsum[cur][wv*17 + nn] = part;
        __syncthreads();                                   // bar 1

        // ---- x(t+1) = out(t), then L1(t+1), both tiles flat ----
        if (t + 1 < Ttot) {
            float osum = blv;
#pragma unroll
            for (int w = 0; w < NW; ++w) osum += wsum[cur][w*17 + nn];
            f32x4 bA0, bA1, bB0 = {0.f,0.f,0.f,0.f}, bB1 = {0.f,0.f,0.f,0.f};
#pragma unroll
            for (int i = 0; i < 4; ++i) {
                bA0[i] = __builtin_fmaf(wih1v[0][i], osum, bias1[0][i]);
                bA1[i] = __builtin_fmaf(wih1v[1][i], osum, bias1[1][i]);
            }
            bA0 = MFMA(a1[0][0], s0, bA0, 0,0,0);  bB0 = MFMA(a1[0][1], s1, bB0, 0,0,0);
            bA1 = MFMA(a1[1][0], s0, bA1, 0,0,0);  bB1 = MFMA(a1[1][1], s1, bB1, 0,0,0);
            f32x4 g10 = bA0 + bB0, g11 = bA1 + bB1;
            float h1n0 = cell_fuse(g10[0], g10[1], g10[2], g10[3], c1[0]);
            float h1n1 = cell_fuse(g11[0], g11[1], g11[2], g11[3], c1[1]);
            if (uvt[0]) Bh[nxt][nn*BST + ut[0]] = f2h(h1n0);
            if (uvt[1]) Bh[nxt][nn*BST + ut[1]] = f2h(h1n1);
            __syncthreads();                               // bar 2 (future only)
        }
    }

    // final output (t = Ttot-1): wsum[(Ttot-1)&1] visible after last barrier
    if (wv == NW-1) {
        float osum = blv;
#pragma unroll
        for (int w = 0; w < NW; ++w) osum += wsum[(Ttot-1)&1][w*17 + nn];
        if (ln < NBB) outp[(size_t)(b0 + ln)*Ttot + (Ttot-1)] = osum;
    }
}

extern "C" void kernel_launch(void* const* d_in, const int* in_sizes, int n_in,
                              void* d_out, int out_size, void* d_ws, size_t ws_size,
                              hipStream_t stream) {
    (void)in_sizes; (void)n_in; (void)out_size; (void)d_ws; (void)ws_size;
    lstm_f16t<<<dim3(Bsz / NBB), dim3(BLK), 0, stream>>>(
        (const float*)d_in[0], (const float*)d_in[1],
        (const float*)d_in[2], (const float*)d_in[3],
        (const float*)d_in[4], (const float*)d_in[5],
        (const float*)d_in[6], (const float*)d_in[7],
        (const float*)d_in[8], (const float*)d_in[9],
        (const float*)d_in[10], (float*)d_out);
}

// Round 4
// 560.007 us; speedup vs baseline: 1.2880x; 1.0390x over previous
//
#include <hip/hip_runtime.h>
#include <stdint.h>

#define Hh    51
#define Bsz   1024
#define Tin   512
#define Ttot  576      // Tin + future(64)
#define NBB   8        // batches per block (grid 128)
#define BROWS 16       // LDS batch rows kept at MFMA N=16; rows 8-15 stay zero
#define NW    7        // waves per block; each wave owns 2 M-tiles (14 >= 13)
#define BLK   (NW*64)  // 448
#define BST   136      // per-batch k-stride (uint16) = 68 dwords (no 4-way alias)

#define L2E   1.4426950408889634f    // log2(e)
#define TL2E  2.8853900817779268f    // 2*log2(e)

typedef __attribute__((ext_vector_type(8))) _Float16 half8;  // 8 x f16 frag
typedef __attribute__((ext_vector_type(4))) float f32x4;     // C/D frag

__device__ __forceinline__ float rcpf(float x){ return __builtin_amdgcn_rcpf(x); }
__device__ __forceinline__ float exp2f_fast(float x){
#if __has_builtin(__builtin_amdgcn_exp2f)
    return __builtin_amdgcn_exp2f(x);
#else
    return exp2f(x);
#endif
}

// Fused LSTM pointwise, rcp-merged: 7 trans ops.
// Inputs pre-scaled: vi,vf,vo by log2e; vg by 2log2e. Updates c, returns h.
__device__ __forceinline__ float cell_fuse(float vi, float vf, float vg,
                                           float vo, float& c){
    float Ei = exp2f_fast(-vi), Ef = exp2f_fast(-vf), Eg = exp2f_fast(-vg);
    float A = 1.f + Ef, B = 1.f + Ei, C = 1.f + Eg, D = 1.f - Eg;
    float BC = B*C;
    float R  = rcpf(A*BC);
    float cn = __builtin_fmaf(c, BC*R, (A*D)*R);
    c = cn;
    float Ec = exp2f_fast(fminf(-cn*TL2E, 120.f));
    float Eo = exp2f_fast(-vo);
    float R2 = rcpf((1.f+Eo)*(1.f+Ec));
    return (1.f - Ec) * R2;
}

__device__ __forceinline__ uint16_t f2h(float f){
    union{ _Float16 h; uint16_t u; } v; v.h = (_Float16)f;   // v_cvt_f16_f32 RNE
    return v.u;
}
#define MFMA __builtin_amdgcn_mfma_f32_16x16x32_f16

// R18: NBB 16->8 + xor-8 lane remap. Per-block MFMA cost is fixed (13 M-tiles)
// but cell cost scales with NBB: with 8 batches, accumulator cols 8-15 are
// don't-care, so after the MFMAs a shfl_xor(.,8) moves tile-1 gate vectors
// from lanes nn<8 into lanes nn>=8 -> each lane runs ONE cell per layer
// (2 cell_fuse/step, was 4; -14 trans -28 VALU -2 cvt -2 ds_write per wave,
// +8 shfl +8 sel). Grid 64->128: idle CUs absorb the doubled block count,
// per-CU issue drops ~25%. Lane nn>=8 owns (u1=4*(wv+7)+quad, batch nn-8);
// its c1/c2 state lives with it across steps. LDS batch rows 8-15 stay zero.
__global__ __launch_bounds__(BLK, 2)
void lstm_f16r(const float* __restrict__ inp,    // [B, Tin]
               const float* __restrict__ Wih1,   // [204, 1]
               const float* __restrict__ Whh1,   // [204, 51]
               const float* __restrict__ bih1,   // [204]
               const float* __restrict__ bhh1,   // [204]
               const float* __restrict__ Wih2,   // [204, 51]
               const float* __restrict__ Whh2,   // [204, 51]
               const float* __restrict__ bih2,   // [204]
               const float* __restrict__ bhh2,   // [204]
               const float* __restrict__ Wl,     // [1, 51]
               const float* __restrict__ blp,    // [1]
               float* __restrict__ outp)         // [B, Ttot]
{
    const int tid = threadIdx.x;
    const int wv  = tid >> 6, ln = tid & 63;
    const int quad = ln >> 4, nn = ln & 15;
    const bool lo = (nn < 8);
    const int b0  = blockIdx.x * NBB;

    __shared__ __align__(16) uint16_t Bh[2][BROWS*BST];
    __shared__ float wsum[2][NW*17];      // parity-dbuf output partials

    for (int k = tid; k < BROWS*BST; k += BLK) { Bh[0][k] = 0; Bh[1][k] = 0; }
    if (tid < NW*17) { wsum[0][tid] = 0.f; wsum[1][tid] = 0.f; }

    // ---- A fragments for 2 tiles; weights pre-scaled by log2e (2log2e for
    // g rows), single f16 product. Wave 6 tile 1 = all-zero dummy. ----
    half8 a1[2][2], a2[2][4];
    f32x4 bias1[2], bias2[2], wih1v[2];
    float wlu[2];
#pragma unroll
    for (int tl = 0; tl < 2; ++tl) {
        const bool tv = (wv + 7*tl) < 13;
        const int lr = 16*(wv + 7*tl) + nn;
        const int ua_ = lr >> 2, ga = lr & 3;
        const bool av = tv && (ua_ < Hh);
        const int pr = av ? (ga*Hh + ua_) : 0;
        const float rs = (ga == 2) ? TL2E : L2E;
#pragma unroll
        for (int s = 0; s < 2; ++s)
#pragma unroll
            for (int j = 0; j < 8; ++j) {
                int k = 32*s + quad*8 + j;
                float w = (av && k < Hh) ? Whh1[pr*Hh + k]*rs : 0.f;
                a1[tl][s][j] = (_Float16)w;
            }
#pragma unroll
        for (int s = 0; s < 4; ++s)
#pragma unroll
            for (int j = 0; j < 8; ++j) {
                int k = 32*s + quad*8 + j;
                float w = 0.f;
                if (av) {
                    if (k < Hh)                    w = Wih2[pr*Hh + k]*rs;
                    else if (k >= 64 && k < 64+Hh) w = Whh2[pr*Hh + (k-64)]*rs;
                }
                a2[tl][s][j] = (_Float16)w;
            }
        const int u = 4*(wv + 7*tl) + quad;
        const bool uv = tv && (u < Hh);
#pragma unroll
        for (int i = 0; i < 4; ++i) {
            int pri = uv ? (i*Hh + u) : 0;
            float gs = (i == 2) ? TL2E : L2E;
            bias1[tl][i] = uv ? (bih1[pri] + bhh1[pri])*gs : 0.f;
            bias2[tl][i] = uv ? (bih2[pri] + bhh2[pri])*gs : 0.f;
            wih1v[tl][i] = uv ? Wih1[pri]*gs : 0.f;
        }
        wlu[tl] = uv ? Wl[u] : 0.f;
    }
    const float blv = blp[0];

    // ---- assigned cell for this lane: (ua, ba); c-state lives here ----
    const int  ua  = 4*(wv + (lo ? 0 : 7)) + quad;
    const bool uva = (ua < Hh);
    const int  ba  = nn & 7;
    const float wlua = lo ? wlu[0] : wlu[1];
    float c1 = 0.f, c2 = 0.f;

    // ---- prologue: h1(0) for assigned cell (pure per-lane math) ----
    {
        float b1a[4], w1a[4];
#pragma unroll
        for (int i = 0; i < 4; ++i) {
            b1a[i] = lo ? bias1[0][i] : bias1[1][i];
            w1a[i] = lo ? wih1v[0][i] : wih1v[1][i];
        }
        float x0 = inp[(size_t)(b0 + ba)*Tin];
        float vi = __builtin_fmaf(w1a[0], x0, b1a[0]);
        float vf = __builtin_fmaf(w1a[1], x0, b1a[1]);
        float vg = __builtin_fmaf(w1a[2], x0, b1a[2]);
        float vo = __builtin_fmaf(w1a[3], x0, b1a[3]);
        float h1n = cell_fuse(vi, vf, vg, vo, c1);
        if (uva) Bh[0][ba*BST + ua] = f2h(h1n);
    }
    float xreg = (lo && Tin > 1) ? inp[(size_t)(b0 + nn)*Tin + 1] : 0.f;  // x(1)
    __syncthreads();

    // ================= input-mode loop: t in [0, Tin-1) =================
    for (int t = 0; t < Tin-1; ++t) {
        const int cur = t & 1, nxt = cur ^ 1;

        // out(t-1) write (wave NW-1 only; reads previous phase's wsum[nxt])
        if (wv == NW-1 && t > 0) {
            float osum = blv;
#pragma unroll
            for (int w = 0; w < NW; ++w) osum += wsum[nxt][w*17 + nn];
            if (ln < NBB) outp[(size_t)(b0 + ln)*Ttot + (t-1)] = osum;
        }
        float xn = (lo && t + 2 < Tin) ? inp[(size_t)(b0 + nn)*Tin + t + 2] : 0.f;

        // ---- one LDS read session: h1(t) slabs 0,1 + h2(t-1) slabs 2,3 ----
        const uint16_t* rb = &Bh[cur][nn*BST + quad*8];
        half8 s0 = *(const half8*)(rb),      s1 = *(const half8*)(rb + 32);
        half8 s2 = *(const half8*)(rb + 64), s3 = *(const half8*)(rb + 96);

        // ---- flat MFMA issue: L2(t) both tiles + L1(t+1) both tiles ----
        f32x4 aA0 = bias2[0], aB0 = {0.f,0.f,0.f,0.f};
        f32x4 aA1 = bias2[1], aB1 = {0.f,0.f,0.f,0.f};
        f32x4 bA0, bA1, bB0 = {0.f,0.f,0.f,0.f}, bB1 = {0.f,0.f,0.f,0.f};
#pragma unroll
        for (int i = 0; i < 4; ++i) {
            bA0[i] = __builtin_fmaf(wih1v[0][i], xreg, bias1[0][i]);
            bA1[i] = __builtin_fmaf(wih1v[1][i], xreg, bias1[1][i]);
        }
        aA0 = MFMA(a2[0][0], s0, aA0, 0,0,0);  aB0 = MFMA(a2[0][1], s1, aB0, 0,0,0);
        aA1 = MFMA(a2[1][0], s0, aA1, 0,0,0);  aB1 = MFMA(a2[1][1], s1, aB1, 0,0,0);
        bA0 = MFMA(a1[0][0], s0, bA0, 0,0,0);  bB0 = MFMA(a1[0][1], s1, bB0, 0,0,0);
        bA1 = MFMA(a1[1][0], s0, bA1, 0,0,0);  bB1 = MFMA(a1[1][1], s1, bB1, 0,0,0);
        aA0 = MFMA(a2[0][2], s2, aA0, 0,0,0);  aB0 = MFMA(a2[0][3], s3, aB0, 0,0,0);
        aA1 = MFMA(a2[1][2], s2, aA1, 0,0,0);  aB1 = MFMA(a2[1][3], s3, aB1, 0,0,0);

        // ---- remap: hi lanes take tile-1 gates from lane^8 ----
        f32x4 g2t0 = aA0 + aB0, g2t1 = aA1 + aB1;
        f32x4 g1t0 = bA0 + bB0, g1t1 = bA1 + bB1;
        float g2[4], g1[4];
#pragma unroll
        for (int i = 0; i < 4; ++i) {
            float h2s = __shfl_xor(g2t1[i], 8, 64);
            float h1s = __shfl_xor(g1t1[i], 8, 64);
            g2[i] = lo ? g2t0[i] : h2s;
            g1[i] = lo ? g1t0[i] : h1s;
        }

        // ---- 2 independent cell chains per lane ----
        float h2v = cell_fuse(g2[0], g2[1], g2[2], g2[3], c2);
        float h1v = cell_fuse(g1[0], g1[1], g1[2], g1[3], c1);

        if (uva) {
            Bh[nxt][ba*BST + 64 + ua] = f2h(h2v);
            Bh[nxt][ba*BST      + ua] = f2h(h1v);
        }
        float part = wlua * h2v;
        part += __shfl_xor(part, 16, 64);
        part += __shfl_xor(part, 32, 64);
        part += __shfl_xor(part, 8, 64);
        if (ln < 8) wsum[cur][wv*17 + ln] = part;

        __syncthreads();
        xreg = xn;
    }

    // ================= future loop: t in [Tin-1, Ttot) =================
    for (int t = Tin-1; t < Ttot; ++t) {
        const int cur = t & 1, nxt = cur ^ 1;

        if (wv == NW-1) {       // t >= 511 > 0 always
            float osum = blv;
#pragma unroll
            for (int w = 0; w < NW; ++w) osum += wsum[nxt][w*17 + nn];
            if (ln < NBB) outp[(size_t)(b0 + ln)*Ttot + (t-1)] = osum;
        }

        const uint16_t* rb = &Bh[cur][nn*BST + quad*8];
        half8 s0 = *(const half8*)(rb),      s1 = *(const half8*)(rb + 32);
        half8 s2 = *(const half8*)(rb + 64), s3 = *(const half8*)(rb + 96);

        // ---- L2(t), both tiles flat ----
        f32x4 aA0 = bias2[0], aB0 = {0.f,0.f,0.f,0.f};
        f32x4 aA1 = bias2[1], aB1 = {0.f,0.f,0.f,0.f};
        aA0 = MFMA(a2[0][0], s0, aA0, 0,0,0);  aB0 = MFMA(a2[0][1], s1, aB0, 0,0,0);
        aA1 = MFMA(a2[1][0], s0, aA1, 0,0,0);  aB1 = MFMA(a2[1][1], s1, aB1, 0,0,0);
        aA0 = MFMA(a2[0][2], s2, aA0, 0,0,0);  aB0 = MFMA(a2[0][3], s3, aB0, 0,0,0);
        aA1 = MFMA(a2[1][2], s2, aA1, 0,0,0);  aB1 = MFMA(a2[1][3], s3, aB1, 0,0,0);
        f32x4 g2t0 = aA0 + aB0, g2t1 = aA1 + aB1;
        float g2[4];
#pragma unroll
        for (int i = 0; i < 4; ++i) {
            float h2s = __shfl_xor(g2t1[i], 8, 64);
            g2[i] = lo ? g2t0[i] : h2s;
        }
        float h2v = cell_fuse(g2[0], g2[1], g2[2], g2[3], c2);
        if (uva) Bh[nxt][ba*BST + 64 + ua] = f2h(h2v);
        float part = wlua * h2v;
        part += __shfl_xor(part, 16, 64);
        part += __shfl_xor(part, 32, 64);
        part += __shfl_xor(part, 8, 64);
        if (ln < 8) wsum[cur][wv*17 + ln] = part;
        __syncthreads();                                   // bar 1

        // ---- x(t+1) = out(t), then L1(t+1), both tiles flat ----
        if (t + 1 < Ttot) {
            float osum = blv;
#pragma unroll
            for (int w = 0; w < NW; ++w) osum += wsum[cur][w*17 + nn];
            f32x4 bA0, bA1, bB0 = {0.f,0.f,0.f,0.f}, bB1 = {0.f,0.f,0.f,0.f};
#pragma unroll
            for (int i = 0; i < 4; ++i) {
                bA0[i] = __builtin_fmaf(wih1v[0][i], osum, bias1[0][i]);
                bA1[i] = __builtin_fmaf(wih1v[1][i], osum, bias1[1][i]);
            }
            bA0 = MFMA(a1[0][0], s0, bA0, 0,0,0);  bB0 = MFMA(a1[0][1], s1, bB0, 0,0,0);
            bA1 = MFMA(a1[1][0], s0, bA1, 0,0,0);  bB1 = MFMA(a1[1][1], s1, bB1, 0,0,0);
            f32x4 g1t0 = bA0 + bB0, g1t1 = bA1 + bB1;
            float g1[4];
#pragma unroll
            for (int i = 0; i < 4; ++i) {
                float h1s = __shfl_xor(g1t1[i], 8, 64);
                g1[i] = lo ? g1t0[i] : h1s;
            }
            float h1v = cell_fuse(g1[0], g1[1], g1[2], g1[3], c1);
            if (uva) Bh[nxt][ba*BST + ua] = f2h(h1v);
            __syncthreads();                               // bar 2 (future only)
        }
    }

    // final output (t = Ttot-1): wsum[(Ttot-1)&1] visible after last barrier
    if (wv == NW-1) {
        float osum = blv;
#pragma unroll
        for (int w = 0; w < NW; ++w) osum += wsum[(Ttot-1)&1][w*17 + nn];
        if (ln < NBB) outp[(size_t)(b0 + ln)*Ttot + (Ttot-1)] = osum;
    }
}

extern "C" void kernel_launch(void* const* d_in, const int* in_sizes, int n_in,
                              void* d_out, int out_size, void* d_ws, size_t ws_size,
                              hipStream_t stream) {
    (void)in_sizes; (void)n_in; (void)out_size; (void)d_ws; (void)ws_size;
    lstm_f16r<<<dim3(Bsz / NBB), dim3(BLK), 0, stream>>>(
        (const float*)d_in[0], (const float*)d_in[1],
        (const float*)d_in[2], (const float*)d_in[3],
        (const float*)d_in[4], (const float*)d_in[5],
        (const float*)d_in[6], (const float*)d_in[7],
        (const float*)d_in[8], (const float*)d_in[9],
        (const float*)d_in[10], (float*)d_out);
}

// Round 6
// 521.830 us; speedup vs baseline: 1.3822x; 1.0732x over previous
//
#include <hip/hip_runtime.h>
#include <stdint.h>

#define Hh    51
#define Bsz   1024
#define Tin   512
#define Ttot  576      // Tin + future(64)
#define NBB   8        // batches per block (grid 128)
#define BROWS 8        // LDS batch rows (mirror trick: cols 8-15 read row nn&7)
#define NW    7        // waves per block; each wave owns 2 M-tiles (14 >= 13)
#define BLK   (NW*64)  // 448
#define BST   136      // per-batch k-stride (uint16) = 68 dwords (no 4-way alias)
#define WS    18       // wsum per-wave stride (16 partials + 2 pad)

#define L2E   1.4426950408889634f    // log2(e)
#define TL2E  2.8853900817779268f    // 2*log2(e)

typedef __attribute__((ext_vector_type(8))) _Float16 half8;  // 8 x f16 frag
typedef __attribute__((ext_vector_type(4))) float f32x4;     // C/D frag

__device__ __forceinline__ float rcpf(float x){ return __builtin_amdgcn_rcpf(x); }
__device__ __forceinline__ float exp2f_fast(float x){
#if __has_builtin(__builtin_amdgcn_exp2f)
    return __builtin_amdgcn_exp2f(x);
#else
    return exp2f(x);
#endif
}

// Fused LSTM pointwise, rcp-merged: 7 trans ops.
// Inputs pre-scaled: vi,vf,vo by log2e; vg by 2log2e. Updates c, returns h.
__device__ __forceinline__ float cell_fuse(float vi, float vf, float vg,
                                           float vo, float& c){
    float Ei = exp2f_fast(-vi), Ef = exp2f_fast(-vf), Eg = exp2f_fast(-vg);
    float A = 1.f + Ef, B = 1.f + Ei, C = 1.f + Eg, D = 1.f - Eg;
    float BC = B*C;
    float R  = rcpf(A*BC);
    float cn = __builtin_fmaf(c, BC*R, (A*D)*R);
    c = cn;
    float Ec = exp2f_fast(fminf(-cn*TL2E, 120.f));
    float Eo = exp2f_fast(-vo);
    float R2 = rcpf((1.f+Eo)*(1.f+Ec));
    return (1.f - Ec) * R2;
}

__device__ __forceinline__ uint16_t f2h(float f){
    union{ _Float16 h; uint16_t u; } v; v.h = (_Float16)f;   // v_cvt_f16_f32 RNE
    return v.u;
}

// quad reduction (sum over lanes ^16 and ^32) via the R4-PROVEN shfl_xor
// chain. R5's inline-asm permlane16/32_swap version failed correctness;
// bisect: this round keeps the mirror-broadcast (audited correct against
// R2-R4's pass evidence) and reverts ONLY the reduction primitive.
__device__ __forceinline__ float qsum(float x){
    x += __shfl_xor(x, 16, 64);
    x += __shfl_xor(x, 32, 64);
    return x;
}
#define MFMA __builtin_amdgcn_mfma_f32_16x16x32_f16

// R20 (= R19 bisect): keep (1) free remap via mirror read: lanes nn>=8
// ds_read row nn&7 (same addr -> LDS broadcast, free), so B cols 8-15 =
// batches 0-7 and tile-1 gates land natively in hi-lane accumulator cols
// (8 ds_bpermutes -> 8 cndmask); Bh rows 8-15 deleted (BROWS=8); (3) B-frag
// ds_reads issued first in the body. Revert (2): wsum reduce back to the
// proven 2x shfl_xor chain (xor8 still gone: 2 partials/wave, reader sums 14).
__global__ __launch_bounds__(BLK, 2)
void lstm_f16b(const float* __restrict__ inp,    // [B, Tin]
               const float* __restrict__ Wih1,   // [204, 1]
               const float* __restrict__ Whh1,   // [204, 51]
               const float* __restrict__ bih1,   // [204]
               const float* __restrict__ bhh1,   // [204]
               const float* __restrict__ Wih2,   // [204, 51]
               const float* __restrict__ Whh2,   // [204, 51]
               const float* __restrict__ bih2,   // [204]
               const float* __restrict__ bhh2,   // [204]
               const float* __restrict__ Wl,     // [1, 51]
               const float* __restrict__ blp,    // [1]
               float* __restrict__ outp)         // [B, Ttot]
{
    const int tid = threadIdx.x;
    const int wv  = tid >> 6, ln = tid & 63;
    const int quad = ln >> 4, nn = ln & 15;
    const bool lo = (nn < 8);
    const int ba  = nn & 7;            // batch owned/read by this lane
    const int b0  = blockIdx.x * NBB;

    __shared__ __align__(16) uint16_t Bh[2][BROWS*BST];
    __shared__ float wsum[2][NW*WS];      // parity-dbuf output partials

    for (int k = tid; k < BROWS*BST; k += BLK) { Bh[0][k] = 0; Bh[1][k] = 0; }
    if (tid < NW*WS) { wsum[0][tid] = 0.f; wsum[1][tid] = 0.f; }

    // ---- A fragments for 2 tiles; weights pre-scaled by log2e (2log2e for
    // g rows), single f16 product. Wave 6 tile 1 = all-zero dummy. ----
    half8 a1[2][2], a2[2][4];
    f32x4 bias1[2], bias2[2], wih1v[2];
    float wlu[2];
#pragma unroll
    for (int tl = 0; tl < 2; ++tl) {
        const bool tv = (wv + 7*tl) < 13;
        const int lr = 16*(wv + 7*tl) + nn;
        const int ua_ = lr >> 2, ga = lr & 3;
        const bool av = tv && (ua_ < Hh);
        const int pr = av ? (ga*Hh + ua_) : 0;
        const float rs = (ga == 2) ? TL2E : L2E;
#pragma unroll
        for (int s = 0; s < 2; ++s)
#pragma unroll
            for (int j = 0; j < 8; ++j) {
                int k = 32*s + quad*8 + j;
                float w = (av && k < Hh) ? Whh1[pr*Hh + k]*rs : 0.f;
                a1[tl][s][j] = (_Float16)w;
            }
#pragma unroll
        for (int s = 0; s < 4; ++s)
#pragma unroll
            for (int j = 0; j < 8; ++j) {
                int k = 32*s + quad*8 + j;
                float w = 0.f;
                if (av) {
                    if (k < Hh)                    w = Wih2[pr*Hh + k]*rs;
                    else if (k >= 64 && k < 64+Hh) w = Whh2[pr*Hh + (k-64)]*rs;
                }
                a2[tl][s][j] = (_Float16)w;
            }
        const int u = 4*(wv + 7*tl) + quad;
        const bool uv = tv && (u < Hh);
#pragma unroll
        for (int i = 0; i < 4; ++i) {
            int pri = uv ? (i*Hh + u) : 0;
            float gs = (i == 2) ? TL2E : L2E;
            bias1[tl][i] = uv ? (bih1[pri] + bhh1[pri])*gs : 0.f;
            bias2[tl][i] = uv ? (bih2[pri] + bhh2[pri])*gs : 0.f;
            wih1v[tl][i] = uv ? Wih1[pri]*gs : 0.f;
        }
        wlu[tl] = uv ? Wl[u] : 0.f;
    }
    const float blv = blp[0];

    // ---- assigned cell for this lane: (ua, ba); c-state lives here ----
    const int  ua  = 4*(wv + (lo ? 0 : 7)) + quad;
    const bool uva = (ua < Hh);
    const float wlua = lo ? wlu[0] : wlu[1];
    float c1 = 0.f, c2 = 0.f;

    // ---- prologue: h1(0) for assigned cell (pure per-lane math) ----
    {
        float b1a[4], w1a[4];
#pragma unroll
        for (int i = 0; i < 4; ++i) {
            b1a[i] = lo ? bias1[0][i] : bias1[1][i];
            w1a[i] = lo ? wih1v[0][i] : wih1v[1][i];
        }
        float x0 = inp[(size_t)(b0 + ba)*Tin];
        float vi = __builtin_fmaf(w1a[0], x0, b1a[0]);
        float vf = __builtin_fmaf(w1a[1], x0, b1a[1]);
        float vg = __builtin_fmaf(w1a[2], x0, b1a[2]);
        float vo = __builtin_fmaf(w1a[3], x0, b1a[3]);
        float h1n = cell_fuse(vi, vf, vg, vo, c1);
        if (uva) Bh[0][ba*BST + ua] = f2h(h1n);
    }
    float xreg = (Tin > 1) ? inp[(size_t)(b0 + ba)*Tin + 1] : 0.f;  // x(1), all lanes
    __syncthreads();

    // ================= input-mode loop: t in [0, Tin-1) =================
    for (int t = 0; t < Tin-1; ++t) {
        const int cur = t & 1, nxt = cur ^ 1;

        // ---- B-frag reads first (start LDS latency early). Lanes nn and
        // nn+8 read the SAME row ba -> broadcast; B cols 8-15 = batches 0-7,
        // so tile-1 MFMAs put their gates natively in hi-lane columns. ----
        const uint16_t* rb = &Bh[cur][ba*BST + quad*8];
        half8 s0 = *(const half8*)(rb),      s1 = *(const half8*)(rb + 32);
        half8 s2 = *(const half8*)(rb + 64), s3 = *(const half8*)(rb + 96);

        // out(t-1) write (wave NW-1 only; reads previous phase's wsum[nxt])
        if (wv == NW-1 && t > 0) {
            float osum = blv;
#pragma unroll
            for (int w = 0; w < NW; ++w)
                osum += wsum[nxt][w*WS + ba] + wsum[nxt][w*WS + 8 + ba];
            if (ln < NBB) outp[(size_t)(b0 + ln)*Ttot + (t-1)] = osum;
        }
        float xn = (t + 2 < Tin) ? inp[(size_t)(b0 + ba)*Tin + t + 2] : 0.f;

        // ---- flat MFMA issue: L2(t) both tiles + L1(t+1) both tiles ----
        f32x4 aA0 = bias2[0], aB0 = {0.f,0.f,0.f,0.f};
        f32x4 aA1 = bias2[1], aB1 = {0.f,0.f,0.f,0.f};
        f32x4 bA0, bA1, bB0 = {0.f,0.f,0.f,0.f}, bB1 = {0.f,0.f,0.f,0.f};
#pragma unroll
        for (int i = 0; i < 4; ++i) {
            bA0[i] = __builtin_fmaf(wih1v[0][i], xreg, bias1[0][i]);
            bA1[i] = __builtin_fmaf(wih1v[1][i], xreg, bias1[1][i]);
        }
        aA0 = MFMA(a2[0][0], s0, aA0, 0,0,0);  aB0 = MFMA(a2[0][1], s1, aB0, 0,0,0);
        aA1 = MFMA(a2[1][0], s0, aA1, 0,0,0);  aB1 = MFMA(a2[1][1], s1, aB1, 0,0,0);
        bA0 = MFMA(a1[0][0], s0, bA0, 0,0,0);  bB0 = MFMA(a1[0][1], s1, bB0, 0,0,0);
        bA1 = MFMA(a1[1][0], s0, bA1, 0,0,0);  bB1 = MFMA(a1[1][1], s1, bB1, 0,0,0);
        aA0 = MFMA(a2[0][2], s2, aA0, 0,0,0);  aB0 = MFMA(a2[0][3], s3, aB0, 0,0,0);
        aA1 = MFMA(a2[1][2], s2, aA1, 0,0,0);  aB1 = MFMA(a2[1][3], s3, aB1, 0,0,0);

        // ---- select own tile's gates (no shuffle needed) ----
        f32x4 g2t0 = aA0 + aB0, g2t1 = aA1 + aB1;
        f32x4 g1t0 = bA0 + bB0, g1t1 = bA1 + bB1;
        float g2[4], g1[4];
#pragma unroll
        for (int i = 0; i < 4; ++i) {
            g2[i] = lo ? g2t0[i] : g2t1[i];
            g1[i] = lo ? g1t0[i] : g1t1[i];
        }

        // ---- 2 independent cell chains per lane; stores issue ASAP ----
        float h2v = cell_fuse(g2[0], g2[1], g2[2], g2[3], c2);
        float h1v = cell_fuse(g1[0], g1[1], g1[2], g1[3], c1);
        if (uva) {
            Bh[nxt][ba*BST + 64 + ua] = f2h(h2v);
            Bh[nxt][ba*BST      + ua] = f2h(h1v);
        }
        // quad reduction; 2 partials/wave (lo tile, hi tile)
        float part = qsum(wlua * h2v);
        if (ln < 16) wsum[cur][wv*WS + ln] = part;

        __syncthreads();
        xreg = xn;
    }

    // ================= future loop: t in [Tin-1, Ttot) =================
    for (int t = Tin-1; t < Ttot; ++t) {
        const int cur = t & 1, nxt = cur ^ 1;

        const uint16_t* rb = &Bh[cur][ba*BST + quad*8];
        half8 s0 = *(const half8*)(rb),      s1 = *(const half8*)(rb + 32);
        half8 s2 = *(const half8*)(rb + 64), s3 = *(const half8*)(rb + 96);

        if (wv == NW-1) {       // t >= 511 > 0 always
            float osum = blv;
#pragma unroll
            for (int w = 0; w < NW; ++w)
                osum += wsum[nxt][w*WS + ba] + wsum[nxt][w*WS + 8 + ba];
            if (ln < NBB) outp[(size_t)(b0 + ln)*Ttot + (t-1)] = osum;
        }

        // ---- L2(t), both tiles flat ----
        f32x4 aA0 = bias2[0], aB0 = {0.f,0.f,0.f,0.f};
        f32x4 aA1 = bias2[1], aB1 = {0.f,0.f,0.f,0.f};
        aA0 = MFMA(a2[0][0], s0, aA0, 0,0,0);  aB0 = MFMA(a2[0][1], s1, aB0, 0,0,0);
        aA1 = MFMA(a2[1][0], s0, aA1, 0,0,0);  aB1 = MFMA(a2[1][1], s1, aB1, 0,0,0);
        aA0 = MFMA(a2[0][2], s2, aA0, 0,0,0);  aB0 = MFMA(a2[0][3], s3, aB0, 0,0,0);
        aA1 = MFMA(a2[1][2], s2, aA1, 0,0,0);  aB1 = MFMA(a2[1][3], s3, aB1, 0,0,0);
        f32x4 g2t0 = aA0 + aB0, g2t1 = aA1 + aB1;
        float g2[4];
#pragma unroll
        for (int i = 0; i < 4; ++i) g2[i] = lo ? g2t0[i] : g2t1[i];
        float h2v = cell_fuse(g2[0], g2[1], g2[2], g2[3], c2);
        if (uva) Bh[nxt][ba*BST + 64 + ua] = f2h(h2v);
        float part = qsum(wlua * h2v);
        if (ln < 16) wsum[cur][wv*WS + ln] = part;
        __syncthreads();                                   // bar 1

        // ---- x(t+1) = out(t), then L1(t+1), both tiles flat ----
        if (t + 1 < Ttot) {
            float osum = blv;
#pragma unroll
            for (int w = 0; w < NW; ++w)
                osum += wsum[cur][w*WS + ba] + wsum[cur][w*WS + 8 + ba];
            f32x4 bA0, bA1, bB0 = {0.f,0.f,0.f,0.f}, bB1 = {0.f,0.f,0.f,0.f};
#pragma unroll
            for (int i = 0; i < 4; ++i) {
                bA0[i] = __builtin_fmaf(wih1v[0][i], osum, bias1[0][i]);
                bA1[i] = __builtin_fmaf(wih1v[1][i], osum, bias1[1][i]);
            }
            bA0 = MFMA(a1[0][0], s0, bA0, 0,0,0);  bB0 = MFMA(a1[0][1], s1, bB0, 0,0,0);
            bA1 = MFMA(a1[1][0], s0, bA1, 0,0,0);  bB1 = MFMA(a1[1][1], s1, bB1, 0,0,0);
            f32x4 g1t0 = bA0 + bB0, g1t1 = bA1 + bB1;
            float g1[4];
#pragma unroll
            for (int i = 0; i < 4; ++i) g1[i] = lo ? g1t0[i] : g1t1[i];
            float h1v = cell_fuse(g1[0], g1[1], g1[2], g1[3], c1);
            if (uva) Bh[nxt][ba*BST + ua] = f2h(h1v);
            __syncthreads();                               // bar 2 (future only)
        }
    }

    // final output (t = Ttot-1): wsum[(Ttot-1)&1] visible after last barrier
    if (wv == NW-1) {
        float osum = blv;
#pragma unroll
        for (int w = 0; w < NW; ++w)
            osum += wsum[(Ttot-1)&1][w*WS + ba] + wsum[(Ttot-1)&1][w*WS + 8 + ba];
        if (ln < NBB) outp[(size_t)(b0 + ln)*Ttot + (Ttot-1)] = osum;
    }
}

extern "C" void kernel_launch(void* const* d_in, const int* in_sizes, int n_in,
                              void* d_out, int out_size, void* d_ws, size_t ws_size,
                              hipStream_t stream) {
    (void)in_sizes; (void)n_in; (void)out_size; (void)d_ws; (void)ws_size;
    lstm_f16b<<<dim3(Bsz / NBB), dim3(BLK), 0, stream>>>(
        (const float*)d_in[0], (const float*)d_in[1],
        (const float*)d_in[2], (const float*)d_in[3],
        (const float*)d_in[4], (const float*)d_in[5],
        (const float*)d_in[6], (const float*)d_in[7],
        (const float*)d_in[8], (const float*)d_in[9],
        (const float*)d_in[10], (float*)d_out);
}